// Round 18
// baseline (821.019 us; speedup 1.0000x reference)
//
#include <hip/hip_runtime.h>
#include <hip/hip_bf16.h>
#include <math.h>

#define B_   8
#define H_   320
#define W_   320
#define HW_  (320*320)

typedef __attribute__((ext_vector_type(8))) short bf16x8;
typedef __attribute__((ext_vector_type(4))) short bf16x4s;
typedef __attribute__((ext_vector_type(4))) float f32x4;

__device__ __forceinline__ short f2b(float v){
    __hip_bfloat16 h = __float2bfloat16(v);
    return *(short*)&h;
}
__device__ __forceinline__ float bf2f(short v){
    unsigned u = ((unsigned)(unsigned short)v) << 16;
    return __uint_as_float(u);
}

// ---------------------------------------------------------------------------
// feat fp32 NCHW -> bf16 NHWC32 + CAM pool (FALLBACK PATH ONLY in r20; the
// merged path folds this into mconv_fg_k and never touches FEAT).
// ---------------------------------------------------------------------------
__global__ void convert_k(const float* __restrict__ in, short* __restrict__ out,
                          float* __restrict__ psum){
    const int b  = blockIdx.y;
    const int px = blockIdx.x*256 + threadIdx.x;
    const float* src = in + (long)b*32*HW_ + px;
    short* dst = out + ((long)b*HW_ + px)*32;
    float f[32];
    short v[32];
    #pragma unroll
    for (int c=0;c<32;++c){ f[c] = src[(long)c*HW_]; v[c] = f2b(f[c]); }
    #pragma unroll
    for (int s=0;s<4;++s)
        *(bf16x8*)(dst + s*8) = *(bf16x8*)(v + s*8);
    #pragma unroll
    for (int c=0;c<32;++c){
        float s = f[c];
        #pragma unroll
        for (int o=1;o<64;o<<=1) s += __shfl_xor(s, o, 64);
        f[c] = s;
    }
    __shared__ float red[4][32];
    const int lane = threadIdx.x & 63, wid = threadIdx.x >> 6;
    if (lane < 32) red[wid][lane] = f[lane];
    __syncthreads();
    if (threadIdx.x < 32)
        atomicAdd(&psum[b*32 + threadIdx.x],
                  red[0][threadIdx.x]+red[1][threadIdx.x]+red[2][threadIdx.x]+red[3][threadIdx.x]);
}

// ---------------------------------------------------------------------------
// Repack ALL conv weights into MFMA A-fragment layout (bf16)  (r6-verified):
//   wr[((chunk*MT + mt)*16 + co_l)*32 + kl]  = W[co = mt*16+co_l][k]
// CIp=32: stored chunk v holds tap t(v) = (v%K)*K + v/K  (kx-major VISIT order
//         to match the ky-chained compute loop; ci = kl).
// CIp=8 : k = tap*CIp + ci (ci fastest), chunk = 4 taps (quad-sliced).
// Zero-padded for co>=COUT, ci>=CIN, tap>=K*K (so NHWC pad channels are 0).
// ---------------------------------------------------------------------------
__global__ void repack_k(const float* __restrict__ sf1, const float* __restrict__ sf2,
                         const float* __restrict__ sg1, const float* __restrict__ sg2,
                         const float* __restrict__ sg3, const float* __restrict__ so1,
                         const float* __restrict__ so2, const float* __restrict__ so3,
                         short* __restrict__ dst){
    const int cum[8]  = {9216,13824,39424,52224,55808,59392,66560,92160};
    const int CINs[8] = {32,32,32,32, 8, 8, 8,24};
    const int CIps[8] = {32,32,32,32, 8, 8, 8,32};
    const int COUTs[8]= {32, 1,32, 8, 8, 8,24,24};
    const int MTs[8]  = { 2, 1, 2, 1, 1, 1, 2, 2};
    const int Ks[8]   = { 3, 3, 5, 5, 5, 5, 5, 5};
    int i = blockIdx.x*256 + threadIdx.x;
    if (i >= 92160) return;
    int s = 0;
    while (i >= cum[s]) ++s;
    const int base = s ? cum[s-1] : 0;
    const int il = i - base;
    const float* src = (s==0)?sf1:(s==1)?sf2:(s==2)?sg1:(s==3)?sg2:(s==4)?sg3:(s==5)?so1:(s==6)?so2:so3;
    const int kl   = il & 31;
    const int co_l = (il >> 5) & 15;
    const int rem  = il >> 9;
    const int MT = MTs[s];
    const int mt = rem % MT;
    const int c  = rem / MT;
    const int K = Ks[s];
    int tap, ci;
    if (CIps[s] == 32){ tap = (c % K)*K + (c / K); ci = kl; }   // visit-order perm
    else              { tap = c*4 + (kl>>3); ci = kl & 7; }
    const int co = mt*16 + co_l;
    float v = 0.f;
    if (co < COUTs[s] && ci < CINs[s] && tap < K*K){
        const int ky = tap / K, kx = tap - ky*K;
        v = src[((co*CINs[s] + ci)*K + ky)*K + kx];
    }
    dst[i] = f2b(v);
}

// ---------------------------------------------------------------------------
// Deform epilogue (verified r2-r11)
// ---------------------------------------------------------------------------
__device__ __forceinline__
float deform_px(const float* val, const float* __restrict__ fus_b,
                const float* __restrict__ gk_b, float inv_s, int y, int x){
    float aff[8]; float sa = 0.f;
    #pragma unroll
    for (int n=0;n<8;++n){
        float a = tanhf(val[16+n]) * inv_s + gk_b[n];
        aff[n] = a; sa += fabsf(a);
    }
    sa += 1e-5f;
    sa = fmaxf(sa, 1.f);
    const float isa = 1.f/sa;
    float ssum = 0.f;
    #pragma unroll
    for (int n=0;n<8;++n){ aff[n] *= isa; ssum += aff[n]; }
    const float aff_ref = 1.f - ssum;

    float o = 0.f;
    #pragma unroll
    for (int k=0;k<9;++k){
        float dy, dx, m;
        if (k == 4){ dy = 0.f; dx = 0.f; m = aff_ref; }
        else {
            const int n = (k < 4) ? k : k-1;
            dy = val[2*n];
            dx = val[2*n+1];
            m  = aff[n];
        }
        float yy = (float)(y + k/3 - 1) + dy;
        float xx = (float)(x + k%3 - 1) + dx;
        float y0f = floorf(yy), x0f = floorf(xx);
        int   y0 = (int)y0f,    x0i = (int)x0f;
        float wy1 = yy - y0f, wy0 = 1.f - wy1;
        float wx1 = xx - x0f, wx0 = 1.f - wx1;
        float v00 = (y0  >=0 && y0  <H_ && x0i  >=0 && x0i  <W_) ? fus_b[ y0   *W_ + x0i  ] : 0.f;
        float v01 = (y0  >=0 && y0  <H_ && x0i+1>=0 && x0i+1<W_) ? fus_b[ y0   *W_ + x0i+1] : 0.f;
        float v10 = (y0+1>=0 && y0+1<H_ && x0i  >=0 && x0i  <W_) ? fus_b[(y0+1)*W_ + x0i  ] : 0.f;
        float v11 = (y0+1>=0 && y0+1<H_ && x0i+1>=0 && x0i+1<W_) ? fus_b[(y0+1)*W_ + x0i+1] : 0.f;
        o += m * (wy0*(wx0*v00 + wx1*v01) + wy1*(wx0*v10 + wx1*v11));
    }
    return fabsf(o);
}

// ---------------------------------------------------------------------------
// MFMA implicit-GEMM conv.  D[co][px] = sum_k W[co][k] * im2col[k][px]
// r18 (verified, 596.8us): seg-plane LDS [seg][y][x][8] (PLANE pad +8),
// rotation-window compute (zero copies), post-use A-column prefetch,
// deform dump stride 25 with ch<24 write guard.
// ---------------------------------------------------------------------------
template<int CIN, int CIp, int COUT, int MT, int K,
         bool IN_BN, bool OUT_STATS, int OUT_MODE, int OCP>
__global__ __launch_bounds__(256, 4)
void mconv_k(const void* __restrict__ inv,
             const float* __restrict__ bn_sum, const float* __restrict__ bn_sq,
             const float* __restrict__ gamma, const float* __restrict__ beta,
             const short* __restrict__ wr, const float* __restrict__ bias,
             void* __restrict__ outv,
             float* __restrict__ osum, float* __restrict__ osq,
             const float* __restrict__ fus, const float* __restrict__ gk,
             const float* __restrict__ aff_scale){
    constexpr int PAD = K/2;
    constexpr int TH  = 8;
    constexpr int LW  = 32 + K - 1;
    constexpr int LH  = TH + K - 1;
    constexpr int SEGS = CIp/8;
    constexpr int PLANE = LH*LW*8 + 8;
    constexpr int NTAPS  = K*K;
    constexpr int NCHUNK = (CIp==32) ? NTAPS : (NTAPS*CIp + 31)/32;
    constexpr int INB  = (CIp==32) ? (SEGS*PLANE*2) : (LH*LW*8*2);
    constexpr int DUMPB = 256*25*4;
    constexpr int LDSB = (OUT_MODE==3 && INB < DUMPB) ? DUMPB : INB;

    __shared__ __align__(16) char ldsraw[LDSB];
    short* lds_in = (short*)ldsraw;
    __shared__ float sc_sh[2][32];
    __shared__ float red[2][4][32];

    const int tid = threadIdx.x;
    const int b   = blockIdx.z;
    const int x0  = blockIdx.x*32, y0 = blockIdx.y*TH;

    const int lane = tid & 63;
    const int wv   = tid >> 6;
    const int pxn  = lane & 15;
    const int quad = lane >> 4;
    const int row0 = 2*wv;

    if (IN_BN){
        if (tid < 32){
            float s = 1.f, sh2 = 0.f;
            if (tid < CIN){
                const float invN = 1.f/(float)(B_*HW_);
                float mu  = bn_sum[tid]*invN;
                float var = bn_sq[tid]*invN - mu*mu;
                s   = gamma[tid] * rsqrtf(var + 1e-5f);
                sh2 = beta[tid] - mu*s;
            }
            sc_sh[0][tid] = s;
            sc_sh[1][tid] = sh2;
        }
        __syncthreads();
    }

    constexpr int KC = (CIp==32) ? K : 1;
    bf16x8 aC[KC][MT];
    bf16x8 aAll[(CIp==8)?NCHUNK:1][MT];

    if constexpr (CIp == 32){
        #pragma unroll
        for (int ky=0; ky<K; ++ky)
            #pragma unroll
            for (int m=0;m<MT;++m)
                aC[ky][m] = *(const bf16x8*)(wr + ((ky*MT + m)*16 + pxn)*32 + quad*8);
    } else {
        #pragma unroll
        for (int c=0;c<NCHUNK;++c)
            #pragma unroll
            for (int m=0;m<MT;++m)
                aAll[c][m] = *(const bf16x8*)(wr + (((c*MT + m)*16 + pxn)*32 + quad*8));
    }

    {
        const short* src = (const short*)inv + (long)b*HW_*CIp;
        constexpr int NU = LH*LW*SEGS;
        constexpr int NIT = (NU + 255)/256;
        bf16x8 vv[NIT];
        int    la[NIT];
        bool   ib[NIT];
        #pragma unroll
        for (int it=0; it<NIT; ++it){
            const int u = tid + it*256;
            bf16x8 v = {0,0,0,0,0,0,0,0};
            bool inb = false;
            int addr = 0;
            if (u < NU){
                const int r   = u / (LW*SEGS);
                const int rem = u - r*(LW*SEGS);
                const int xl  = rem / SEGS;
                const int seg = rem - xl*SEGS;
                const int gy = y0 + r - PAD, gx = x0 + xl - PAD;
                addr = seg*PLANE + (r*LW + xl)*8;
                inb = (gy>=0 && gy<H_ && gx>=0 && gx<W_);
                if (inb)
                    v = *(const bf16x8*)(src + ((long)gy*W_ + gx)*CIp + seg*8);
            }
            vv[it] = v; la[it] = addr; ib[it] = inb;
        }
        __builtin_amdgcn_sched_barrier(0);
        #pragma unroll
        for (int it=0; it<NIT; ++it){
            const int u = tid + it*256;
            if (u < NU){
                bf16x8 v = vv[it];
                if (IN_BN && ib[it]){
                    const int seg = u - (u/SEGS)*SEGS;
                    #pragma unroll
                    for (int j=0;j<8;++j){
                        float f = bf2f(v[j]);
                        f = fmaxf(fmaf(f, sc_sh[0][seg*8+j], sc_sh[1][seg*8+j]), 0.f);
                        v[j] = f2b(f);
                    }
                }
                *(bf16x8*)&lds_in[la[it]] = v;
            }
        }
    }
    __syncthreads();

    const f32x4 zero = {0.f, 0.f, 0.f, 0.f};
    f32x4 acc[2][MT][2];
    #pragma unroll
    for (int rr=0;rr<2;++rr)
        #pragma unroll
        for (int m=0;m<MT;++m){ acc[rr][m][0] = zero; acc[rr][m][1] = zero; }

    if constexpr (CIp == 32){
        const short* bbase = lds_in + quad*PLANE + (row0*LW + pxn)*8;
        #pragma unroll
        for (int kx=0; kx<K; ++kx){
            bf16x8 bw[3][2];
            #pragma unroll
            for (int r=0;r<2;++r)
                #pragma unroll
                for (int n=0;n<2;++n)
                    bw[r][n] = *(const bf16x8*)(bbase + (r*LW + kx + n*16)*8);
            __builtin_amdgcn_sched_barrier(0);
            #pragma unroll
            for (int ky=0; ky<K; ++ky){
                if (ky < K-1){
                    #pragma unroll
                    for (int n=0;n<2;++n)
                        bw[(ky+2)%3][n] = *(const bf16x8*)(bbase + ((ky+2)*LW + kx + n*16)*8);
                }
                __builtin_amdgcn_sched_barrier(0);
                #pragma unroll
                for (int m=0;m<MT;++m){
                    acc[0][m][0] = __builtin_amdgcn_mfma_f32_16x16x32_bf16(aC[ky][m], bw[ky%3][0],     acc[0][m][0], 0,0,0);
                    acc[0][m][1] = __builtin_amdgcn_mfma_f32_16x16x32_bf16(aC[ky][m], bw[ky%3][1],     acc[0][m][1], 0,0,0);
                    acc[1][m][0] = __builtin_amdgcn_mfma_f32_16x16x32_bf16(aC[ky][m], bw[(ky+1)%3][0], acc[1][m][0], 0,0,0);
                    acc[1][m][1] = __builtin_amdgcn_mfma_f32_16x16x32_bf16(aC[ky][m], bw[(ky+1)%3][1], acc[1][m][1], 0,0,0);
                }
                if (kx+1 < K){
                    #pragma unroll
                    for (int m=0;m<MT;++m)
                        aC[ky][m] = *(const bf16x8*)(wr + ((((kx+1)*K+ky)*MT + m)*16 + pxn)*32 + quad*8);
                }
            }
        }
    } else {
        auto bptr = [&](int c, int rr)->const short*{
            const int row = row0 + rr;
            int t = c*4 + quad;
            if (t >= NTAPS) t = 0;
            const int ky = t / K, kx = t - ky*K;
            return lds_in + ((row+ky)*LW + kx + pxn)*8;
        };

        bf16x8 bcp[2][2][2];
        #pragma unroll
        for (int rr=0;rr<2;++rr){
            const short* bp = bptr(0, rr);
            bcp[0][rr][0] = *(const bf16x8*)bp;
            bcp[0][rr][1] = *(const bf16x8*)(bp + 16*8);
        }

        #pragma unroll
        for (int c=0; c<NCHUNK; ++c){
            if (c+1 < NCHUNK){
                #pragma unroll
                for (int rr=0;rr<2;++rr){
                    const short* bpn = bptr(c+1, rr);
                    bcp[(c+1)&1][rr][0] = *(const bf16x8*)bpn;
                    bcp[(c+1)&1][rr][1] = *(const bf16x8*)(bpn + 16*8);
                }
            }
            __builtin_amdgcn_sched_barrier(0);
            #pragma unroll
            for (int m=0;m<MT;++m)
                #pragma unroll
                for (int rr=0;rr<2;++rr){
                    acc[rr][m][0] = __builtin_amdgcn_mfma_f32_16x16x32_bf16(aAll[c][m], bcp[c&1][rr][0], acc[rr][m][0], 0,0,0);
                    acc[rr][m][1] = __builtin_amdgcn_mfma_f32_16x16x32_bf16(aAll[c][m], bcp[c&1][rr][1], acc[rr][m][1], 0,0,0);
                }
        }
    }

    if (OUT_STATS){
        #pragma unroll
        for (int m=0;m<MT;++m){
            #pragma unroll
            for (int r=0;r<4;++r){
                float v  = acc[0][m][0][r] + acc[0][m][1][r]
                         + acc[1][m][0][r] + acc[1][m][1][r];
                float v2 = acc[0][m][0][r]*acc[0][m][0][r] + acc[0][m][1][r]*acc[0][m][1][r]
                         + acc[1][m][0][r]*acc[1][m][0][r] + acc[1][m][1][r]*acc[1][m][1][r];
                #pragma unroll
                for (int o=1;o<16;o<<=1){
                    v  += __shfl_xor(v,  o, 64);
                    v2 += __shfl_xor(v2, o, 64);
                }
                if (pxn == 0){
                    red[0][wv][m*16 + quad*4 + r] = v;
                    red[1][wv][m*16 + quad*4 + r] = v2;
                }
            }
        }
        __syncthreads();
        if (tid < MT*16 && tid < COUT){
            atomicAdd(&osum[tid], red[0][0][tid]+red[0][1][tid]+red[0][2][tid]+red[0][3][tid]);
            atomicAdd(&osq[tid],  red[1][0][tid]+red[1][1][tid]+red[1][2][tid]+red[1][3][tid]);
        }
    }

    if (OUT_MODE == 3){
        float* out = (float*)outv;
        __syncthreads();
        float* dumpf = (float*)ldsraw;
        #pragma unroll
        for (int rr=0;rr<2;++rr){
            const int row = row0 + rr;
            #pragma unroll
            for (int m=0;m<MT;++m){
                if (m*16 + quad*4 < 24){
                    #pragma unroll
                    for (int n=0;n<2;++n)
                        #pragma unroll
                        for (int r=0;r<4;++r)
                            dumpf[(row*32 + n*16 + pxn)*25 + (m*16 + quad*4 + r)] = acc[rr][m][n][r];
                }
            }
        }
        __syncthreads();
        {
            float val[24];
            #pragma unroll
            for (int c2=0;c2<24;++c2) val[c2] = dumpf[tid*25 + c2] + bias[c2];
            const int yy = y0 + (tid>>5), xx = x0 + (tid&31);
            const float inv_s = 1.f/(aff_scale[0] + 1e-5f);
            out[(long)b*HW_ + yy*W_ + xx] =
                deform_px(val, fus + (long)b*HW_, gk + b*8, inv_s, yy, xx);
        }
    } else if (OUT_MODE == 2){
        float* out = (float*)outv;
        #pragma unroll
        for (int rr=0;rr<2;++rr){
            const int y = y0 + row0 + rr;
            #pragma unroll
            for (int m=0;m<MT;++m){
                #pragma unroll
                for (int r=0;r<4;++r){
                    const int co = m*16 + quad*4 + r;
                    if (co < COUT){
                        float* op = out + (((long)b*COUT + co)*H_ + y)*W_ + x0;
                        #pragma unroll
                        for (int n=0;n<2;++n)
                            op[n*16 + pxn] = tanhf(acc[rr][m][n][r] + bias[co]);
                    }
                }
            }
        }
    } else {
        short* o = (short*)outv;
        #pragma unroll
        for (int rr=0;rr<2;++rr){
            const int y = y0 + row0 + rr;
            #pragma unroll
            for (int m=0;m<MT;++m){
                const int co0 = m*16 + quad*4;
                if (co0 < OCP){
                    #pragma unroll
                    for (int n=0;n<2;++n){
                        bf16x4s pk;
                        #pragma unroll
                        for (int r=0;r<4;++r){
                            float f = acc[rr][m][n][r];
                            if (OUT_MODE == 1) f += bias[co0+r];
                            pk[r] = f2b(f);
                        }
                        const long px = ((long)b*H_ + y)*W_ + x0 + n*16 + pxn;
                        *(bf16x4s*)(o + px*OCP + co0) = pk;
                    }
                }
            }
        }
    }
}

// ---------------------------------------------------------------------------
// r19/r20: MERGED f1(K=3)+g1(K=5). r20: stages DIRECTLY from fp32 NCHW feat
// (convert fused; FEAT buffer + convert_k dispatch eliminated) and computes
// the CAM pool over the block's exclusively-owned interior pixels (LDS
// atomics -> 1 global atomic/ch/block). bf16 values identical to convert_k's
// (same f2b of same fp32) -> conv outputs bitwise-identical to r19.
// ---------------------------------------------------------------------------
template<int KK, int OFF>
__device__ __forceinline__
void conv_core32(const short* __restrict__ lds_in, const short* __restrict__ wr,
                 int row0, int pxn, int quad, f32x4 acc[2][2][2]){
    constexpr int LW = 36;
    constexpr int PLANE = 12*36*8 + 8;
    const short* bbase = lds_in + quad*PLANE + ((row0+OFF)*LW + OFF + pxn)*8;
    bf16x8 aC[KK][2];
    #pragma unroll
    for (int ky=0; ky<KK; ++ky)
        #pragma unroll
        for (int m=0;m<2;++m)
            aC[ky][m] = *(const bf16x8*)(wr + ((ky*2 + m)*16 + pxn)*32 + quad*8);
    #pragma unroll
    for (int kx=0; kx<KK; ++kx){
        bf16x8 bw[3][2];
        #pragma unroll
        for (int r=0;r<2;++r)
            #pragma unroll
            for (int n=0;n<2;++n)
                bw[r][n] = *(const bf16x8*)(bbase + (r*LW + kx + n*16)*8);
        __builtin_amdgcn_sched_barrier(0);
        #pragma unroll
        for (int ky=0; ky<KK; ++ky){
            if (ky < KK-1){
                #pragma unroll
                for (int n=0;n<2;++n)
                    bw[(ky+2)%3][n] = *(const bf16x8*)(bbase + ((ky+2)*LW + kx + n*16)*8);
            }
            __builtin_amdgcn_sched_barrier(0);
            #pragma unroll
            for (int m=0;m<2;++m){
                acc[0][m][0] = __builtin_amdgcn_mfma_f32_16x16x32_bf16(aC[ky][m], bw[ky%3][0],     acc[0][m][0], 0,0,0);
                acc[0][m][1] = __builtin_amdgcn_mfma_f32_16x16x32_bf16(aC[ky][m], bw[ky%3][1],     acc[0][m][1], 0,0,0);
                acc[1][m][0] = __builtin_amdgcn_mfma_f32_16x16x32_bf16(aC[ky][m], bw[(ky+1)%3][0], acc[1][m][0], 0,0,0);
                acc[1][m][1] = __builtin_amdgcn_mfma_f32_16x16x32_bf16(aC[ky][m], bw[(ky+1)%3][1], acc[1][m][1], 0,0,0);
            }
            if (kx+1 < KK){
                #pragma unroll
                for (int m=0;m<2;++m)
                    aC[ky][m] = *(const bf16x8*)(wr + ((((kx+1)*KK+ky)*2 + m)*16 + pxn)*32 + quad*8);
            }
        }
    }
}

__global__ __launch_bounds__(256, 4)
void mconv_fg_k(const float* __restrict__ featf,
                const short* __restrict__ wf, const short* __restrict__ wg,
                short* __restrict__ f1o, short* __restrict__ g1o,
                float* __restrict__ sum0, float* __restrict__ sq0,
                float* __restrict__ sum1, float* __restrict__ sq1,
                float* __restrict__ psum){
    constexpr int PAD = 2, LW = 36, LH = 12;
    constexpr int PLANE = LH*LW*8 + 8;

    __shared__ __align__(16) char ldsraw[4*PLANE*2];
    short* lds_in = (short*)ldsraw;
    __shared__ float red[2][4][32];
    __shared__ float psl[32];

    const int tid = threadIdx.x;
    const int b   = blockIdx.z;
    const int x0  = blockIdx.x*32, y0 = blockIdx.y*8;

    const int lane = tid & 63;
    const int wv   = tid >> 6;
    const int pxn  = lane & 15;
    const int quad = lane >> 4;
    const int row0 = 2*wv;

    if (tid < 32) psl[tid] = 0.f;
    __syncthreads();

    // ---- stage fp32 NCHW -> bf16 LDS (K=5 halo) + pool interior pixels ----
    {
        const float* srcb = featf + (long)b*32*HW_;
        #pragma unroll
        for (int it=0; it<2; ++it){
            const int upx = tid + it*256;
            const bool valid = upx < LH*LW;
            const int r  = valid ? (upx / LW) : 0;
            const int xl = upx - r*LW;
            const int gy = y0 + r - PAD, gx = x0 + xl - PAD;
            const bool inb = valid && gy>=0 && gy<H_ && gx>=0 && gx<W_;
            float f[32];
            if (inb){
                const float* sp = srcb + (long)gy*W_ + gx;
                #pragma unroll
                for (int c=0;c<32;++c) f[c] = sp[(long)c*HW_];
            } else {
                #pragma unroll
                for (int c=0;c<32;++c) f[c] = 0.f;
            }
            if (valid){
                short v[32];
                #pragma unroll
                for (int c=0;c<32;++c) v[c] = f2b(f[c]);
                #pragma unroll
                for (int s=0;s<4;++s)
                    *(bf16x8*)&lds_in[s*PLANE + (r*LW + xl)*8] = *(bf16x8*)(v + s*8);
            }
            // pool: this block exclusively owns interior pixels (gy in
            // [y0,y0+8), gx in [x0,x0+32)) <=> r in [2,10), xl in [2,34)
            if (valid && r>=PAD && r<PAD+8 && xl>=PAD && xl<PAD+32){
                #pragma unroll
                for (int c=0;c<32;++c) atomicAdd(&psl[c], f[c]);
            }
        }
    }
    __syncthreads();
    if (tid < 32) atomicAdd(&psum[b*32 + tid], psl[tid]);

    const f32x4 zero = {0.f, 0.f, 0.f, 0.f};
    f32x4 acc[2][2][2];

    // ==== phase 1: f1 (K=3, interior offset +1) ====
    #pragma unroll
    for (int rr=0;rr<2;++rr)
        #pragma unroll
        for (int m=0;m<2;++m){ acc[rr][m][0] = zero; acc[rr][m][1] = zero; }
    conv_core32<3,1>(lds_in, wf, row0, pxn, quad, acc);
    #pragma unroll
    for (int m=0;m<2;++m)
        #pragma unroll
        for (int r=0;r<4;++r){
            float v  = acc[0][m][0][r] + acc[0][m][1][r] + acc[1][m][0][r] + acc[1][m][1][r];
            float v2 = acc[0][m][0][r]*acc[0][m][0][r] + acc[0][m][1][r]*acc[0][m][1][r]
                     + acc[1][m][0][r]*acc[1][m][0][r] + acc[1][m][1][r]*acc[1][m][1][r];
            #pragma unroll
            for (int o=1;o<16;o<<=1){ v += __shfl_xor(v, o, 64); v2 += __shfl_xor(v2, o, 64); }
            if (pxn == 0){ red[0][wv][m*16+quad*4+r] = v; red[1][wv][m*16+quad*4+r] = v2; }
        }
    __syncthreads();
    if (tid < 32){
        atomicAdd(&sum0[tid], red[0][0][tid]+red[0][1][tid]+red[0][2][tid]+red[0][3][tid]);
        atomicAdd(&sq0[tid],  red[1][0][tid]+red[1][1][tid]+red[1][2][tid]+red[1][3][tid]);
    }
    #pragma unroll
    for (int rr=0;rr<2;++rr){
        const int y = y0 + row0 + rr;
        #pragma unroll
        for (int m=0;m<2;++m){
            const int co0 = m*16 + quad*4;
            #pragma unroll
            for (int n=0;n<2;++n){
                bf16x4s pk;
                #pragma unroll
                for (int r=0;r<4;++r) pk[r] = f2b(acc[rr][m][n][r]);
                const long px = ((long)b*H_ + y)*W_ + x0 + n*16 + pxn;
                *(bf16x4s*)(f1o + px*32 + co0) = pk;
            }
        }
    }
    __syncthreads();   // protect red before phase 2 reuse

    // ==== phase 2: g1 (K=5, offset 0) ====
    #pragma unroll
    for (int rr=0;rr<2;++rr)
        #pragma unroll
        for (int m=0;m<2;++m){ acc[rr][m][0] = zero; acc[rr][m][1] = zero; }
    conv_core32<5,0>(lds_in, wg, row0, pxn, quad, acc);
    #pragma unroll
    for (int m=0;m<2;++m)
        #pragma unroll
        for (int r=0;r<4;++r){
            float v  = acc[0][m][0][r] + acc[0][m][1][r] + acc[1][m][0][r] + acc[1][m][1][r];
            float v2 = acc[0][m][0][r]*acc[0][m][0][r] + acc[0][m][1][r]*acc[0][m][1][r]
                     + acc[1][m][0][r]*acc[1][m][0][r] + acc[1][m][1][r]*acc[1][m][1][r];
            #pragma unroll
            for (int o=1;o<16;o<<=1){ v += __shfl_xor(v, o, 64); v2 += __shfl_xor(v2, o, 64); }
            if (pxn == 0){ red[0][wv][m*16+quad*4+r] = v; red[1][wv][m*16+quad*4+r] = v2; }
        }
    __syncthreads();
    if (tid < 32){
        atomicAdd(&sum1[tid], red[0][0][tid]+red[0][1][tid]+red[0][2][tid]+red[0][3][tid]);
        atomicAdd(&sq1[tid],  red[1][0][tid]+red[1][1][tid]+red[1][2][tid]+red[1][3][tid]);
    }
    #pragma unroll
    for (int rr=0;rr<2;++rr){
        const int y = y0 + row0 + rr;
        #pragma unroll
        for (int m=0;m<2;++m){
            const int co0 = m*16 + quad*4;
            #pragma unroll
            for (int n=0;n<2;++n){
                bf16x4s pk;
                #pragma unroll
                for (int r=0;r<4;++r) pk[r] = f2b(acc[rr][m][n][r]);
                const long px = ((long)b*H_ + y)*W_ + x0 + n*16 + pxn;
                *(bf16x4s*)(g1o + px*32 + co0) = pk;
            }
        }
    }
}

// ---------------------------------------------------------------------------
// CAM MLP (32->16 celu ->16 celu ->1 relu +0.001) then gauss_win -> gk (B,8)
// ---------------------------------------------------------------------------
__global__ void sigma_k(const float* __restrict__ p,
                        const float* s1w, const float* s1b,
                        const float* s2w, const float* s2b,
                        const float* s3w, const float* s3b,
                        float* __restrict__ gk){
    const int b = threadIdx.x;
    if (b >= B_) return;
    float pb[32];
    for (int j=0;j<32;++j) pb[j] = p[b*32+j] * (1.f/(float)HW_);
    float h1[16], h2[16];
    for (int i=0;i<16;++i){
        float t = s1b[i];
        for (int j=0;j<32;++j) t = fmaf(pb[j], s1w[i*32+j], t);
        h1[i] = t > 0.f ? t : expm1f(t);          // celu(alpha=1)
    }
    for (int i=0;i<16;++i){
        float t = s2b[i];
        for (int j=0;j<16;++j) t = fmaf(h1[j], s2w[i*16+j], t);
        h2[i] = t > 0.f ? t : expm1f(t);
    }
    float t = s3b[0];
    for (int j=0;j<16;++j) t = fmaf(h2[j], s3w[j], t);
    float sigma = fmaxf(t, 0.f) + 0.001f;
    float sg = sigma + 0.2f;                      // sigma_gamma = 0.2
    float e = expf(-1.f/(2.f*sg*sg));
    float inv = 1.f/(2.f*e + 1.f);
    float a = e*inv, c = inv;                     // w1 = [a, c, a]
    float* g = gk + b*8;                          // outer(w1,w1) flat minus center
    g[0]=a*a; g[1]=a*c; g[2]=a*a; g[3]=c*a; g[4]=c*a; g[5]=a*a; g[6]=a*c; g[7]=a*a;
}

// ---------------------------------------------------------------------------
extern "C" void kernel_launch(void* const* d_in, const int* in_sizes, int n_in,
                              void* d_out, int out_size, void* d_ws, size_t ws_size,
                              hipStream_t stream){
    const float* feat    = (const float*)d_in[0];
    const float* g1_w    = (const float*)d_in[1];
    const float* g1_g    = (const float*)d_in[2];
    const float* g1_b    = (const float*)d_in[3];
    const float* g2_w    = (const float*)d_in[4];
    const float* g2_g    = (const float*)d_in[5];
    const float* g2_b    = (const float*)d_in[6];
    const float* g3_w    = (const float*)d_in[7];
    const float* g3_bias = (const float*)d_in[8];
    const float* f1_w    = (const float*)d_in[9];
    const float* f1_g    = (const float*)d_in[10];
    const float* f1_b    = (const float*)d_in[11];
    const float* f2_w    = (const float*)d_in[12];
    const float* f2_bias = (const float*)d_in[13];
    const float* s1w     = (const float*)d_in[14];
    const float* s1b     = (const float*)d_in[15];
    const float* s2w     = (const float*)d_in[16];
    const float* s2b     = (const float*)d_in[17];
    const float* s3w     = (const float*)d_in[18];
    const float* s3b     = (const float*)d_in[19];
    const float* oa1_w   = (const float*)d_in[20];
    const float* oa1_g   = (const float*)d_in[21];
    const float* oa1_b   = (const float*)d_in[22];
    const float* oa2_w   = (const float*)d_in[23];
    const float* oa2_g   = (const float*)d_in[24];
    const float* oa2_b   = (const float*)d_in[25];
    const float* oa3_w   = (const float*)d_in[26];
    const float* oa3_bias= (const float*)d_in[27];
    const float* aff_scale=(const float*)d_in[28];
    float* out = (float*)d_out;

    // workspace: bf16 NHWC intermediates
    char* ws = (char*)d_ws;
    short* FEAT = (short*)(ws + 0L);             // fallback path only
    short* A1   = (short*)(ws + 52428800L);
    short* A2   = (short*)(ws + 104857600L);
    short* GUID = (short*)(ws + 117964800L);
    float* FUS  = (float*)(ws + 131072000L);
    float* SM   = (float*)(ws + 134348800L);
    short* OA2  = A1;   // alias: A1 dead before oa2 writes
    short* G1O  = (short*)(ws + 0L);             // r20: merged path reuses FEAT slot
    const bool merged = (ws_size >= 134348800UL + 4096UL*400UL);  // r19-proven layout

    float* sum = SM;             // 5 slots x 64
    float* sq  = SM + 320;
    float* p   = SM + 640;       // 256 (channel sums, fused pool)
    float* gk  = SM + 896;       // 64
    short* WBs = (short*)(SM + 960);   // bf16 MFMA weights, 92160 shorts
    short* w_f1 = WBs + 0;
    short* w_f2 = WBs + 9216;
    short* w_g1 = WBs + 13824;
    short* w_g2 = WBs + 39424;
    short* w_g3 = WBs + 52224;
    short* w_o1 = WBs + 55808;
    short* w_o2 = WBs + 59392;
    short* w_o3 = WBs + 66560;

    hipMemsetAsync(sum, 0, 896*sizeof(float), stream);   // zero sum+sumsq+p

    repack_k<<<dim3(360), dim3(256), 0, stream>>>(
        f1_w, f2_w, g1_w, g2_w, g3_w, oa1_w, oa2_w, oa3_w, WBs);

    const dim3 cgrid(10, 40, 8), cblk(256);
    #define MCONV(CIN,CIp,COUT,MT,K,IBN,OST,OM,OCP) \
        mconv_k<CIN,CIp,COUT,MT,K,IBN,OST,OM,OCP><<<cgrid,cblk,0,stream>>>

    const short* G1SRC;
    if (merged){
        // r20: fg stages from fp32 feat directly (convert_k eliminated);
        // also computes pool -> p. g1 output goes to the freed FEAT slot.
        mconv_fg_k<<<cgrid, cblk, 0, stream>>>(feat, w_f1, w_g1, A1, G1O,
                                               sum+0*64, sq+0*64, sum+1*64, sq+1*64, p);
        sigma_k<<<dim3(1), dim3(64), 0, stream>>>(p, s1w, s1b, s2w, s2b, s3w, s3b, gk);
        // f2 (bn in, 3x3 32->1, tanh) reads A1
        MCONV(32,32, 1,1,3,true ,false,2, 0)(A1, sum+0*64, sq+0*64, f1_g, f1_b,
            w_f2, f2_bias, FUS, nullptr, nullptr, nullptr, nullptr, nullptr);
        G1SRC = G1O;
    } else {
        // fallback = r18 sequence with convert_k
        convert_k<<<dim3(HW_/256, B_), dim3(256), 0, stream>>>(feat, FEAT, p);
        sigma_k<<<dim3(1), dim3(64), 0, stream>>>(p, s1w, s1b, s2w, s2b, s3w, s3b, gk);
        MCONV(32,32,32,2,3,false,true ,0,32)(FEAT, nullptr, nullptr, nullptr, nullptr,
            w_f1, nullptr, A1, sum+0*64, sq+0*64, nullptr, nullptr, nullptr);
        MCONV(32,32, 1,1,3,true ,false,2, 0)(A1, sum+0*64, sq+0*64, f1_g, f1_b,
            w_f2, f2_bias, FUS, nullptr, nullptr, nullptr, nullptr, nullptr);
        MCONV(32,32,32,2,5,false,true ,0,32)(FEAT, nullptr, nullptr, nullptr, nullptr,
            w_g1, nullptr, A1, sum+1*64, sq+1*64, nullptr, nullptr, nullptr);
        G1SRC = A1;
    }

    // guid branch: g2 (5x5 32->8, stats) -> g3 (5x5 8->8 +bias)
    MCONV(32,32, 8,1,5,true ,true ,0, 8)(G1SRC, sum+1*64, sq+1*64, g1_g, g1_b,
        w_g2, nullptr, A2, sum+2*64, sq+2*64, nullptr, nullptr, nullptr);
    MCONV( 8, 8, 8,1,5,true ,false,1, 8)(A2, sum+2*64, sq+2*64, g2_g, g2_b,
        w_g3, g3_bias, GUID, nullptr, nullptr, nullptr, nullptr, nullptr);

    // off_aff branch: oa1 (5x5 8->8, stats) -> oa2 (5x5 8->24, stats)
    //                 -> oa3 (5x5 24->24 +bias) fused with deform -> out
    MCONV( 8, 8, 8,1,5,false,true ,0, 8)(GUID, nullptr, nullptr, nullptr, nullptr,
        w_o1, nullptr, A2, sum+3*64, sq+3*64, nullptr, nullptr, nullptr);
    MCONV( 8, 8,24,2,5,true ,true ,0,32)(A2, sum+3*64, sq+3*64, oa1_g, oa1_b,
        w_o2, nullptr, OA2, sum+4*64, sq+4*64, nullptr, nullptr, nullptr);
    MCONV(24,32,24,2,5,true ,false,3, 0)(OA2, sum+4*64, sq+4*64, oa2_g, oa2_b,
        w_o3, oa3_bias, out, nullptr, nullptr, FUS, gk, aff_scale);
    #undef MCONV
}

// Round 22
// 565.649 us; speedup vs baseline: 1.4515x; 1.4515x over previous
//
#include <hip/hip_runtime.h>
#include <hip/hip_bf16.h>
#include <math.h>

#define B_   8
#define H_   320
#define W_   320
#define HW_  (320*320)

typedef __attribute__((ext_vector_type(8))) short bf16x8;
typedef __attribute__((ext_vector_type(4))) short bf16x4s;
typedef __attribute__((ext_vector_type(4))) float f32x4;

__device__ __forceinline__ short f2b(float v){
    __hip_bfloat16 h = __float2bfloat16(v);
    return *(short*)&h;
}
__device__ __forceinline__ float bf2f(short v){
    unsigned u = ((unsigned)(unsigned short)v) << 16;
    return __uint_as_float(u);
}

// ---------------------------------------------------------------------------
// feat fp32 NCHW -> bf16 NHWC32, FUSED with CAM global-avg-pool partial sums
// (r20 lesson: this transpose NEEDS its own coalesced kernel shape — fusing
// it into halo-tiled conv staging over-fetched 2x and was 4.5x slower.)
// ---------------------------------------------------------------------------
__global__ void convert_k(const float* __restrict__ in, short* __restrict__ out,
                          float* __restrict__ psum){
    const int b  = blockIdx.y;
    const int px = blockIdx.x*256 + threadIdx.x;
    const float* src = in + (long)b*32*HW_ + px;
    short* dst = out + ((long)b*HW_ + px)*32;
    float f[32];
    short v[32];
    #pragma unroll
    for (int c=0;c<32;++c){ f[c] = src[(long)c*HW_]; v[c] = f2b(f[c]); }
    #pragma unroll
    for (int s=0;s<4;++s)
        *(bf16x8*)(dst + s*8) = *(bf16x8*)(v + s*8);
    #pragma unroll
    for (int c=0;c<32;++c){
        float s = f[c];
        #pragma unroll
        for (int o=1;o<64;o<<=1) s += __shfl_xor(s, o, 64);
        f[c] = s;
    }
    __shared__ float red[4][32];
    const int lane = threadIdx.x & 63, wid = threadIdx.x >> 6;
    if (lane < 32) red[wid][lane] = f[lane];
    __syncthreads();
    if (threadIdx.x < 32)
        atomicAdd(&psum[b*32 + threadIdx.x],
                  red[0][threadIdx.x]+red[1][threadIdx.x]+red[2][threadIdx.x]+red[3][threadIdx.x]);
}

// ---------------------------------------------------------------------------
// Repack ALL conv weights into MFMA A-fragment layout (bf16)  (r6-verified):
//   wr[((chunk*MT + mt)*16 + co_l)*32 + kl]  = W[co = mt*16+co_l][k]
// CIp=32: stored chunk v holds tap t(v) = (v%K)*K + v/K  (kx-major VISIT order
//         to match the ky-chained compute loop; ci = kl).
// CIp=8 : k = tap*CIp + ci (ci fastest), chunk = 4 taps (quad-sliced).
// Zero-padded for co>=COUT, ci>=CIN, tap>=K*K (so NHWC pad channels are 0).
// ---------------------------------------------------------------------------
__global__ void repack_k(const float* __restrict__ sf1, const float* __restrict__ sf2,
                         const float* __restrict__ sg1, const float* __restrict__ sg2,
                         const float* __restrict__ sg3, const float* __restrict__ so1,
                         const float* __restrict__ so2, const float* __restrict__ so3,
                         short* __restrict__ dst){
    const int cum[8]  = {9216,13824,39424,52224,55808,59392,66560,92160};
    const int CINs[8] = {32,32,32,32, 8, 8, 8,24};
    const int CIps[8] = {32,32,32,32, 8, 8, 8,32};
    const int COUTs[8]= {32, 1,32, 8, 8, 8,24,24};
    const int MTs[8]  = { 2, 1, 2, 1, 1, 1, 2, 2};
    const int Ks[8]   = { 3, 3, 5, 5, 5, 5, 5, 5};
    int i = blockIdx.x*256 + threadIdx.x;
    if (i >= 92160) return;
    int s = 0;
    while (i >= cum[s]) ++s;
    const int base = s ? cum[s-1] : 0;
    const int il = i - base;
    const float* src = (s==0)?sf1:(s==1)?sf2:(s==2)?sg1:(s==3)?sg2:(s==4)?sg3:(s==5)?so1:(s==6)?so2:so3;
    const int kl   = il & 31;
    const int co_l = (il >> 5) & 15;
    const int rem  = il >> 9;
    const int MT = MTs[s];
    const int mt = rem % MT;
    const int c  = rem / MT;
    const int K = Ks[s];
    int tap, ci;
    if (CIps[s] == 32){ tap = (c % K)*K + (c / K); ci = kl; }   // visit-order perm
    else              { tap = c*4 + (kl>>3); ci = kl & 7; }
    const int co = mt*16 + co_l;
    float v = 0.f;
    if (co < COUTs[s] && ci < CINs[s] && tap < K*K){
        const int ky = tap / K, kx = tap - ky*K;
        v = src[((co*CINs[s] + ci)*K + ky)*K + kx];
    }
    dst[i] = f2b(v);
}

// ---------------------------------------------------------------------------
// Deform epilogue (verified r2-r11)
// ---------------------------------------------------------------------------
__device__ __forceinline__
float deform_px(const float* val, const float* __restrict__ fus_b,
                const float* __restrict__ gk_b, float inv_s, int y, int x){
    float aff[8]; float sa = 0.f;
    #pragma unroll
    for (int n=0;n<8;++n){
        float a = tanhf(val[16+n]) * inv_s + gk_b[n];
        aff[n] = a; sa += fabsf(a);
    }
    sa += 1e-5f;
    sa = fmaxf(sa, 1.f);
    const float isa = 1.f/sa;
    float ssum = 0.f;
    #pragma unroll
    for (int n=0;n<8;++n){ aff[n] *= isa; ssum += aff[n]; }
    const float aff_ref = 1.f - ssum;

    float o = 0.f;
    #pragma unroll
    for (int k=0;k<9;++k){
        float dy, dx, m;
        if (k == 4){ dy = 0.f; dx = 0.f; m = aff_ref; }
        else {
            const int n = (k < 4) ? k : k-1;
            dy = val[2*n];
            dx = val[2*n+1];
            m  = aff[n];
        }
        float yy = (float)(y + k/3 - 1) + dy;
        float xx = (float)(x + k%3 - 1) + dx;
        float y0f = floorf(yy), x0f = floorf(xx);
        int   y0 = (int)y0f,    x0i = (int)x0f;
        float wy1 = yy - y0f, wy0 = 1.f - wy1;
        float wx1 = xx - x0f, wx0 = 1.f - wx1;
        float v00 = (y0  >=0 && y0  <H_ && x0i  >=0 && x0i  <W_) ? fus_b[ y0   *W_ + x0i  ] : 0.f;
        float v01 = (y0  >=0 && y0  <H_ && x0i+1>=0 && x0i+1<W_) ? fus_b[ y0   *W_ + x0i+1] : 0.f;
        float v10 = (y0+1>=0 && y0+1<H_ && x0i  >=0 && x0i  <W_) ? fus_b[(y0+1)*W_ + x0i  ] : 0.f;
        float v11 = (y0+1>=0 && y0+1<H_ && x0i+1>=0 && x0i+1<W_) ? fus_b[(y0+1)*W_ + x0i+1] : 0.f;
        o += m * (wy0*(wx0*v00 + wx1*v01) + wy1*(wx0*v10 + wx1*v11));
    }
    return fabsf(o);
}

// ---------------------------------------------------------------------------
// MFMA implicit-GEMM conv.  D[co][px] = sum_k W[co][k] * im2col[k][px]
// r18 (verified, 596.8us): seg-plane LDS [seg][y][x][8] (PLANE pad +8),
// rotation-window compute (zero copies), post-use A-column prefetch,
// deform dump stride 25 with ch<24 write guard.
// ---------------------------------------------------------------------------
template<int CIN, int CIp, int COUT, int MT, int K,
         bool IN_BN, bool OUT_STATS, int OUT_MODE, int OCP>
__global__ __launch_bounds__(256, 4)
void mconv_k(const void* __restrict__ inv,
             const float* __restrict__ bn_sum, const float* __restrict__ bn_sq,
             const float* __restrict__ gamma, const float* __restrict__ beta,
             const short* __restrict__ wr, const float* __restrict__ bias,
             void* __restrict__ outv,
             float* __restrict__ osum, float* __restrict__ osq,
             const float* __restrict__ fus, const float* __restrict__ gk,
             const float* __restrict__ aff_scale){
    constexpr int PAD = K/2;
    constexpr int TH  = 8;
    constexpr int LW  = 32 + K - 1;
    constexpr int LH  = TH + K - 1;
    constexpr int SEGS = CIp/8;
    constexpr int PLANE = LH*LW*8 + 8;
    constexpr int NTAPS  = K*K;
    constexpr int NCHUNK = (CIp==32) ? NTAPS : (NTAPS*CIp + 31)/32;
    constexpr int INB  = (CIp==32) ? (SEGS*PLANE*2) : (LH*LW*8*2);
    constexpr int DUMPB = 256*25*4;
    constexpr int LDSB = (OUT_MODE==3 && INB < DUMPB) ? DUMPB : INB;

    __shared__ __align__(16) char ldsraw[LDSB];
    short* lds_in = (short*)ldsraw;
    __shared__ float sc_sh[2][32];
    __shared__ float red[2][4][32];

    const int tid = threadIdx.x;
    const int b   = blockIdx.z;
    const int x0  = blockIdx.x*32, y0 = blockIdx.y*TH;

    const int lane = tid & 63;
    const int wv   = tid >> 6;
    const int pxn  = lane & 15;
    const int quad = lane >> 4;
    const int row0 = 2*wv;

    if (IN_BN){
        if (tid < 32){
            float s = 1.f, sh2 = 0.f;
            if (tid < CIN){
                const float invN = 1.f/(float)(B_*HW_);
                float mu  = bn_sum[tid]*invN;
                float var = bn_sq[tid]*invN - mu*mu;
                s   = gamma[tid] * rsqrtf(var + 1e-5f);
                sh2 = beta[tid] - mu*s;
            }
            sc_sh[0][tid] = s;
            sc_sh[1][tid] = sh2;
        }
        __syncthreads();
    }

    constexpr int KC = (CIp==32) ? K : 1;
    bf16x8 aC[KC][MT];
    bf16x8 aAll[(CIp==8)?NCHUNK:1][MT];

    if constexpr (CIp == 32){
        #pragma unroll
        for (int ky=0; ky<K; ++ky)
            #pragma unroll
            for (int m=0;m<MT;++m)
                aC[ky][m] = *(const bf16x8*)(wr + ((ky*MT + m)*16 + pxn)*32 + quad*8);
    } else {
        #pragma unroll
        for (int c=0;c<NCHUNK;++c)
            #pragma unroll
            for (int m=0;m<MT;++m)
                aAll[c][m] = *(const bf16x8*)(wr + (((c*MT + m)*16 + pxn)*32 + quad*8));
    }

    {
        const short* src = (const short*)inv + (long)b*HW_*CIp;
        constexpr int NU = LH*LW*SEGS;
        constexpr int NIT = (NU + 255)/256;
        bf16x8 vv[NIT];
        int    la[NIT];
        bool   ib[NIT];
        #pragma unroll
        for (int it=0; it<NIT; ++it){
            const int u = tid + it*256;
            bf16x8 v = {0,0,0,0,0,0,0,0};
            bool inb = false;
            int addr = 0;
            if (u < NU){
                const int r   = u / (LW*SEGS);
                const int rem = u - r*(LW*SEGS);
                const int xl  = rem / SEGS;
                const int seg = rem - xl*SEGS;
                const int gy = y0 + r - PAD, gx = x0 + xl - PAD;
                addr = seg*PLANE + (r*LW + xl)*8;
                inb = (gy>=0 && gy<H_ && gx>=0 && gx<W_);
                if (inb)
                    v = *(const bf16x8*)(src + ((long)gy*W_ + gx)*CIp + seg*8);
            }
            vv[it] = v; la[it] = addr; ib[it] = inb;
        }
        __builtin_amdgcn_sched_barrier(0);
        #pragma unroll
        for (int it=0; it<NIT; ++it){
            const int u = tid + it*256;
            if (u < NU){
                bf16x8 v = vv[it];
                if (IN_BN && ib[it]){
                    const int seg = u - (u/SEGS)*SEGS;
                    #pragma unroll
                    for (int j=0;j<8;++j){
                        float f = bf2f(v[j]);
                        f = fmaxf(fmaf(f, sc_sh[0][seg*8+j], sc_sh[1][seg*8+j]), 0.f);
                        v[j] = f2b(f);
                    }
                }
                *(bf16x8*)&lds_in[la[it]] = v;
            }
        }
    }
    __syncthreads();

    const f32x4 zero = {0.f, 0.f, 0.f, 0.f};
    f32x4 acc[2][MT][2];
    #pragma unroll
    for (int rr=0;rr<2;++rr)
        #pragma unroll
        for (int m=0;m<MT;++m){ acc[rr][m][0] = zero; acc[rr][m][1] = zero; }

    if constexpr (CIp == 32){
        const short* bbase = lds_in + quad*PLANE + (row0*LW + pxn)*8;
        #pragma unroll
        for (int kx=0; kx<K; ++kx){
            bf16x8 bw[3][2];
            #pragma unroll
            for (int r=0;r<2;++r)
                #pragma unroll
                for (int n=0;n<2;++n)
                    bw[r][n] = *(const bf16x8*)(bbase + (r*LW + kx + n*16)*8);
            __builtin_amdgcn_sched_barrier(0);
            #pragma unroll
            for (int ky=0; ky<K; ++ky){
                if (ky < K-1){
                    #pragma unroll
                    for (int n=0;n<2;++n)
                        bw[(ky+2)%3][n] = *(const bf16x8*)(bbase + ((ky+2)*LW + kx + n*16)*8);
                }
                __builtin_amdgcn_sched_barrier(0);
                #pragma unroll
                for (int m=0;m<MT;++m){
                    acc[0][m][0] = __builtin_amdgcn_mfma_f32_16x16x32_bf16(aC[ky][m], bw[ky%3][0],     acc[0][m][0], 0,0,0);
                    acc[0][m][1] = __builtin_amdgcn_mfma_f32_16x16x32_bf16(aC[ky][m], bw[ky%3][1],     acc[0][m][1], 0,0,0);
                    acc[1][m][0] = __builtin_amdgcn_mfma_f32_16x16x32_bf16(aC[ky][m], bw[(ky+1)%3][0], acc[1][m][0], 0,0,0);
                    acc[1][m][1] = __builtin_amdgcn_mfma_f32_16x16x32_bf16(aC[ky][m], bw[(ky+1)%3][1], acc[1][m][1], 0,0,0);
                }
                if (kx+1 < K){
                    #pragma unroll
                    for (int m=0;m<MT;++m)
                        aC[ky][m] = *(const bf16x8*)(wr + ((((kx+1)*K+ky)*MT + m)*16 + pxn)*32 + quad*8);
                }
            }
        }
    } else {
        auto bptr = [&](int c, int rr)->const short*{
            const int row = row0 + rr;
            int t = c*4 + quad;
            if (t >= NTAPS) t = 0;
            const int ky = t / K, kx = t - ky*K;
            return lds_in + ((row+ky)*LW + kx + pxn)*8;
        };

        bf16x8 bcp[2][2][2];
        #pragma unroll
        for (int rr=0;rr<2;++rr){
            const short* bp = bptr(0, rr);
            bcp[0][rr][0] = *(const bf16x8*)bp;
            bcp[0][rr][1] = *(const bf16x8*)(bp + 16*8);
        }

        #pragma unroll
        for (int c=0; c<NCHUNK; ++c){
            if (c+1 < NCHUNK){
                #pragma unroll
                for (int rr=0;rr<2;++rr){
                    const short* bpn = bptr(c+1, rr);
                    bcp[(c+1)&1][rr][0] = *(const bf16x8*)bpn;
                    bcp[(c+1)&1][rr][1] = *(const bf16x8*)(bpn + 16*8);
                }
            }
            __builtin_amdgcn_sched_barrier(0);
            #pragma unroll
            for (int m=0;m<MT;++m)
                #pragma unroll
                for (int rr=0;rr<2;++rr){
                    acc[rr][m][0] = __builtin_amdgcn_mfma_f32_16x16x32_bf16(aAll[c][m], bcp[c&1][rr][0], acc[rr][m][0], 0,0,0);
                    acc[rr][m][1] = __builtin_amdgcn_mfma_f32_16x16x32_bf16(aAll[c][m], bcp[c&1][rr][1], acc[rr][m][1], 0,0,0);
                }
        }
    }

    if (OUT_STATS){
        #pragma unroll
        for (int m=0;m<MT;++m){
            #pragma unroll
            for (int r=0;r<4;++r){
                float v  = acc[0][m][0][r] + acc[0][m][1][r]
                         + acc[1][m][0][r] + acc[1][m][1][r];
                float v2 = acc[0][m][0][r]*acc[0][m][0][r] + acc[0][m][1][r]*acc[0][m][1][r]
                         + acc[1][m][0][r]*acc[1][m][0][r] + acc[1][m][1][r]*acc[1][m][1][r];
                #pragma unroll
                for (int o=1;o<16;o<<=1){
                    v  += __shfl_xor(v,  o, 64);
                    v2 += __shfl_xor(v2, o, 64);
                }
                if (pxn == 0){
                    red[0][wv][m*16 + quad*4 + r] = v;
                    red[1][wv][m*16 + quad*4 + r] = v2;
                }
            }
        }
        __syncthreads();
        if (tid < MT*16 && tid < COUT){
            atomicAdd(&osum[tid], red[0][0][tid]+red[0][1][tid]+red[0][2][tid]+red[0][3][tid]);
            atomicAdd(&osq[tid],  red[1][0][tid]+red[1][1][tid]+red[1][2][tid]+red[1][3][tid]);
        }
    }

    if (OUT_MODE == 3){
        float* out = (float*)outv;
        __syncthreads();
        float* dumpf = (float*)ldsraw;
        #pragma unroll
        for (int rr=0;rr<2;++rr){
            const int row = row0 + rr;
            #pragma unroll
            for (int m=0;m<MT;++m){
                if (m*16 + quad*4 < 24){
                    #pragma unroll
                    for (int n=0;n<2;++n)
                        #pragma unroll
                        for (int r=0;r<4;++r)
                            dumpf[(row*32 + n*16 + pxn)*25 + (m*16 + quad*4 + r)] = acc[rr][m][n][r];
                }
            }
        }
        __syncthreads();
        {
            float val[24];
            #pragma unroll
            for (int c2=0;c2<24;++c2) val[c2] = dumpf[tid*25 + c2] + bias[c2];
            const int yy = y0 + (tid>>5), xx = x0 + (tid&31);
            const float inv_s = 1.f/(aff_scale[0] + 1e-5f);
            out[(long)b*HW_ + yy*W_ + xx] =
                deform_px(val, fus + (long)b*HW_, gk + b*8, inv_s, yy, xx);
        }
    } else if (OUT_MODE == 2){
        float* out = (float*)outv;
        #pragma unroll
        for (int rr=0;rr<2;++rr){
            const int y = y0 + row0 + rr;
            #pragma unroll
            for (int m=0;m<MT;++m){
                #pragma unroll
                for (int r=0;r<4;++r){
                    const int co = m*16 + quad*4 + r;
                    if (co < COUT){
                        float* op = out + (((long)b*COUT + co)*H_ + y)*W_ + x0;
                        #pragma unroll
                        for (int n=0;n<2;++n)
                            op[n*16 + pxn] = tanhf(acc[rr][m][n][r] + bias[co]);
                    }
                }
            }
        }
    } else {
        short* o = (short*)outv;
        #pragma unroll
        for (int rr=0;rr<2;++rr){
            const int y = y0 + row0 + rr;
            #pragma unroll
            for (int m=0;m<MT;++m){
                const int co0 = m*16 + quad*4;
                if (co0 < OCP){
                    #pragma unroll
                    for (int n=0;n<2;++n){
                        bf16x4s pk;
                        #pragma unroll
                        for (int r=0;r<4;++r){
                            float f = acc[rr][m][n][r];
                            if (OUT_MODE == 1) f += bias[co0+r];
                            pk[r] = f2b(f);
                        }
                        const long px = ((long)b*H_ + y)*W_ + x0 + n*16 + pxn;
                        *(bf16x4s*)(o + px*OCP + co0) = pk;
                    }
                }
            }
        }
    }
}

// ---------------------------------------------------------------------------
// r19 (verified 569.2us): MERGED f1(K=3)+g1(K=5) — stages FEAT ONCE (K=5 halo
// superset), runs both convs sequentially from the same LDS tile. f1 reads
// the interior at row/col offset +1. Per-conv MFMA order identical to
// mconv_k -> bitwise-identical outputs. Saves one 52MB staging pass +
// one dispatch (f1 compute adds only ~13us to g1's kernel).
// ---------------------------------------------------------------------------
template<int KK, int OFF>
__device__ __forceinline__
void conv_core32(const short* __restrict__ lds_in, const short* __restrict__ wr,
                 int row0, int pxn, int quad, f32x4 acc[2][2][2]){
    constexpr int LW = 36;
    constexpr int PLANE = 12*36*8 + 8;
    const short* bbase = lds_in + quad*PLANE + ((row0+OFF)*LW + OFF + pxn)*8;
    bf16x8 aC[KK][2];
    #pragma unroll
    for (int ky=0; ky<KK; ++ky)
        #pragma unroll
        for (int m=0;m<2;++m)
            aC[ky][m] = *(const bf16x8*)(wr + ((ky*2 + m)*16 + pxn)*32 + quad*8);
    #pragma unroll
    for (int kx=0; kx<KK; ++kx){
        bf16x8 bw[3][2];
        #pragma unroll
        for (int r=0;r<2;++r)
            #pragma unroll
            for (int n=0;n<2;++n)
                bw[r][n] = *(const bf16x8*)(bbase + (r*LW + kx + n*16)*8);
        __builtin_amdgcn_sched_barrier(0);
        #pragma unroll
        for (int ky=0; ky<KK; ++ky){
            if (ky < KK-1){
                #pragma unroll
                for (int n=0;n<2;++n)
                    bw[(ky+2)%3][n] = *(const bf16x8*)(bbase + ((ky+2)*LW + kx + n*16)*8);
            }
            __builtin_amdgcn_sched_barrier(0);
            #pragma unroll
            for (int m=0;m<2;++m){
                acc[0][m][0] = __builtin_amdgcn_mfma_f32_16x16x32_bf16(aC[ky][m], bw[ky%3][0],     acc[0][m][0], 0,0,0);
                acc[0][m][1] = __builtin_amdgcn_mfma_f32_16x16x32_bf16(aC[ky][m], bw[ky%3][1],     acc[0][m][1], 0,0,0);
                acc[1][m][0] = __builtin_amdgcn_mfma_f32_16x16x32_bf16(aC[ky][m], bw[(ky+1)%3][0], acc[1][m][0], 0,0,0);
                acc[1][m][1] = __builtin_amdgcn_mfma_f32_16x16x32_bf16(aC[ky][m], bw[(ky+1)%3][1], acc[1][m][1], 0,0,0);
            }
            if (kx+1 < KK){
                #pragma unroll
                for (int m=0;m<2;++m)
                    aC[ky][m] = *(const bf16x8*)(wr + ((((kx+1)*KK+ky)*2 + m)*16 + pxn)*32 + quad*8);
            }
        }
    }
}

__global__ __launch_bounds__(256, 4)
void mconv_fg_k(const short* __restrict__ feat,
                const short* __restrict__ wf, const short* __restrict__ wg,
                short* __restrict__ f1o, short* __restrict__ g1o,
                float* __restrict__ sum0, float* __restrict__ sq0,
                float* __restrict__ sum1, float* __restrict__ sq1){
    constexpr int PAD = 2, LW = 36, LH = 12, SEGS = 4;
    constexpr int PLANE = LH*LW*8 + 8;

    __shared__ __align__(16) char ldsraw[SEGS*PLANE*2];
    short* lds_in = (short*)ldsraw;
    __shared__ float red[2][4][32];

    const int tid = threadIdx.x;
    const int b   = blockIdx.z;
    const int x0  = blockIdx.x*32, y0 = blockIdx.y*8;

    const int lane = tid & 63;
    const int wv   = tid >> 6;
    const int pxn  = lane & 15;
    const int quad = lane >> 4;
    const int row0 = 2*wv;

    // ---- stage FEAT once (K=5 halo, no BN) ----
    {
        const short* src = feat + (long)b*HW_*32;
        constexpr int NU = LH*LW*SEGS;
        constexpr int NIT = (NU + 255)/256;
        bf16x8 vv[NIT];
        int    la[NIT];
        #pragma unroll
        for (int it=0; it<NIT; ++it){
            const int u = tid + it*256;
            bf16x8 v = {0,0,0,0,0,0,0,0};
            int addr = 0;
            if (u < NU){
                const int r   = u / (LW*SEGS);
                const int rem = u - r*(LW*SEGS);
                const int xl  = rem / SEGS;
                const int seg = rem - xl*SEGS;
                const int gy = y0 + r - PAD, gx = x0 + xl - PAD;
                addr = seg*PLANE + (r*LW + xl)*8;
                if (gy>=0 && gy<H_ && gx>=0 && gx<W_)
                    v = *(const bf16x8*)(src + ((long)gy*W_ + gx)*32 + seg*8);
            }
            vv[it] = v; la[it] = addr;
        }
        __builtin_amdgcn_sched_barrier(0);
        #pragma unroll
        for (int it=0; it<NIT; ++it){
            if (tid + it*256 < NU)
                *(bf16x8*)&lds_in[la[it]] = vv[it];
        }
    }
    __syncthreads();

    const f32x4 zero = {0.f, 0.f, 0.f, 0.f};
    f32x4 acc[2][2][2];

    // ==== phase 1: f1 (K=3, interior offset +1) ====
    #pragma unroll
    for (int rr=0;rr<2;++rr)
        #pragma unroll
        for (int m=0;m<2;++m){ acc[rr][m][0] = zero; acc[rr][m][1] = zero; }
    conv_core32<3,1>(lds_in, wf, row0, pxn, quad, acc);
    #pragma unroll
    for (int m=0;m<2;++m)
        #pragma unroll
        for (int r=0;r<4;++r){
            float v  = acc[0][m][0][r] + acc[0][m][1][r] + acc[1][m][0][r] + acc[1][m][1][r];
            float v2 = acc[0][m][0][r]*acc[0][m][0][r] + acc[0][m][1][r]*acc[0][m][1][r]
                     + acc[1][m][0][r]*acc[1][m][0][r] + acc[1][m][1][r]*acc[1][m][1][r];
            #pragma unroll
            for (int o=1;o<16;o<<=1){ v += __shfl_xor(v, o, 64); v2 += __shfl_xor(v2, o, 64); }
            if (pxn == 0){ red[0][wv][m*16+quad*4+r] = v; red[1][wv][m*16+quad*4+r] = v2; }
        }
    __syncthreads();
    if (tid < 32){
        atomicAdd(&sum0[tid], red[0][0][tid]+red[0][1][tid]+red[0][2][tid]+red[0][3][tid]);
        atomicAdd(&sq0[tid],  red[1][0][tid]+red[1][1][tid]+red[1][2][tid]+red[1][3][tid]);
    }
    #pragma unroll
    for (int rr=0;rr<2;++rr){
        const int y = y0 + row0 + rr;
        #pragma unroll
        for (int m=0;m<2;++m){
            const int co0 = m*16 + quad*4;
            #pragma unroll
            for (int n=0;n<2;++n){
                bf16x4s pk;
                #pragma unroll
                for (int r=0;r<4;++r) pk[r] = f2b(acc[rr][m][n][r]);
                const long px = ((long)b*H_ + y)*W_ + x0 + n*16 + pxn;
                *(bf16x4s*)(f1o + px*32 + co0) = pk;
            }
        }
    }
    __syncthreads();   // protect red before phase 2 reuse

    // ==== phase 2: g1 (K=5, offset 0) ====
    #pragma unroll
    for (int rr=0;rr<2;++rr)
        #pragma unroll
        for (int m=0;m<2;++m){ acc[rr][m][0] = zero; acc[rr][m][1] = zero; }
    conv_core32<5,0>(lds_in, wg, row0, pxn, quad, acc);
    #pragma unroll
    for (int m=0;m<2;++m)
        #pragma unroll
        for (int r=0;r<4;++r){
            float v  = acc[0][m][0][r] + acc[0][m][1][r] + acc[1][m][0][r] + acc[1][m][1][r];
            float v2 = acc[0][m][0][r]*acc[0][m][0][r] + acc[0][m][1][r]*acc[0][m][1][r]
                     + acc[1][m][0][r]*acc[1][m][0][r] + acc[1][m][1][r]*acc[1][m][1][r];
            #pragma unroll
            for (int o=1;o<16;o<<=1){ v += __shfl_xor(v, o, 64); v2 += __shfl_xor(v2, o, 64); }
            if (pxn == 0){ red[0][wv][m*16+quad*4+r] = v; red[1][wv][m*16+quad*4+r] = v2; }
        }
    __syncthreads();
    if (tid < 32){
        atomicAdd(&sum1[tid], red[0][0][tid]+red[0][1][tid]+red[0][2][tid]+red[0][3][tid]);
        atomicAdd(&sq1[tid],  red[1][0][tid]+red[1][1][tid]+red[1][2][tid]+red[1][3][tid]);
    }
    #pragma unroll
    for (int rr=0;rr<2;++rr){
        const int y = y0 + row0 + rr;
        #pragma unroll
        for (int m=0;m<2;++m){
            const int co0 = m*16 + quad*4;
            #pragma unroll
            for (int n=0;n<2;++n){
                bf16x4s pk;
                #pragma unroll
                for (int r=0;r<4;++r) pk[r] = f2b(acc[rr][m][n][r]);
                const long px = ((long)b*H_ + y)*W_ + x0 + n*16 + pxn;
                *(bf16x4s*)(g1o + px*32 + co0) = pk;
            }
        }
    }
}

// ---------------------------------------------------------------------------
// CAM MLP (32->16 celu ->16 celu ->1 relu +0.001) then gauss_win -> gk (B,8)
// ---------------------------------------------------------------------------
__global__ void sigma_k(const float* __restrict__ p,
                        const float* s1w, const float* s1b,
                        const float* s2w, const float* s2b,
                        const float* s3w, const float* s3b,
                        float* __restrict__ gk){
    const int b = threadIdx.x;
    if (b >= B_) return;
    float pb[32];
    for (int j=0;j<32;++j) pb[j] = p[b*32+j] * (1.f/(float)HW_);
    float h1[16], h2[16];
    for (int i=0;i<16;++i){
        float t = s1b[i];
        for (int j=0;j<32;++j) t = fmaf(pb[j], s1w[i*32+j], t);
        h1[i] = t > 0.f ? t : expm1f(t);          // celu(alpha=1)
    }
    for (int i=0;i<16;++i){
        float t = s2b[i];
        for (int j=0;j<16;++j) t = fmaf(h1[j], s2w[i*16+j], t);
        h2[i] = t > 0.f ? t : expm1f(t);
    }
    float t = s3b[0];
    for (int j=0;j<16;++j) t = fmaf(h2[j], s3w[j], t);
    float sigma = fmaxf(t, 0.f) + 0.001f;
    float sg = sigma + 0.2f;                      // sigma_gamma = 0.2
    float e = expf(-1.f/(2.f*sg*sg));
    float inv = 1.f/(2.f*e + 1.f);
    float a = e*inv, c = inv;                     // w1 = [a, c, a]
    float* g = gk + b*8;                          // outer(w1,w1) flat minus center
    g[0]=a*a; g[1]=a*c; g[2]=a*a; g[3]=c*a; g[4]=c*a; g[5]=a*a; g[6]=a*c; g[7]=a*a;
}

// ---------------------------------------------------------------------------
extern "C" void kernel_launch(void* const* d_in, const int* in_sizes, int n_in,
                              void* d_out, int out_size, void* d_ws, size_t ws_size,
                              hipStream_t stream){
    const float* feat    = (const float*)d_in[0];
    const float* g1_w    = (const float*)d_in[1];
    const float* g1_g    = (const float*)d_in[2];
    const float* g1_b    = (const float*)d_in[3];
    const float* g2_w    = (const float*)d_in[4];
    const float* g2_g    = (const float*)d_in[5];
    const float* g2_b    = (const float*)d_in[6];
    const float* g3_w    = (const float*)d_in[7];
    const float* g3_bias = (const float*)d_in[8];
    const float* f1_w    = (const float*)d_in[9];
    const float* f1_g    = (const float*)d_in[10];
    const float* f1_b    = (const float*)d_in[11];
    const float* f2_w    = (const float*)d_in[12];
    const float* f2_bias = (const float*)d_in[13];
    const float* s1w     = (const float*)d_in[14];
    const float* s1b     = (const float*)d_in[15];
    const float* s2w     = (const float*)d_in[16];
    const float* s2b     = (const float*)d_in[17];
    const float* s3w     = (const float*)d_in[18];
    const float* s3b     = (const float*)d_in[19];
    const float* oa1_w   = (const float*)d_in[20];
    const float* oa1_g   = (const float*)d_in[21];
    const float* oa1_b   = (const float*)d_in[22];
    const float* oa2_w   = (const float*)d_in[23];
    const float* oa2_g   = (const float*)d_in[24];
    const float* oa2_b   = (const float*)d_in[25];
    const float* oa3_w   = (const float*)d_in[26];
    const float* oa3_bias= (const float*)d_in[27];
    const float* aff_scale=(const float*)d_in[28];
    float* out = (float*)d_out;

    // workspace: bf16 NHWC intermediates
    char* ws = (char*)d_ws;
    short* FEAT = (short*)(ws + 0L);
    short* A1   = (short*)(ws + 52428800L);
    short* A2   = (short*)(ws + 104857600L);
    short* GUID = (short*)(ws + 117964800L);
    float* FUS  = (float*)(ws + 131072000L);
    float* SM   = (float*)(ws + 134348800L);
    short* OA2  = A1;   // alias: A1 dead before oa2 writes
    short* G1O  = (short*)(ws + 135266304L);     // merged-path g1 output (52.4MB)
    const bool merged = (ws_size >= 135266304UL + 52428800UL);

    float* sum = SM;             // 5 slots x 64
    float* sq  = SM + 320;
    float* p   = SM + 640;       // 256 (channel sums, fused pool)
    float* gk  = SM + 896;       // 64
    short* WBs = (short*)(SM + 960);   // bf16 MFMA weights, 92160 shorts
    short* w_f1 = WBs + 0;
    short* w_f2 = WBs + 9216;
    short* w_g1 = WBs + 13824;
    short* w_g2 = WBs + 39424;
    short* w_g3 = WBs + 52224;
    short* w_o1 = WBs + 55808;
    short* w_o2 = WBs + 59392;
    short* w_o3 = WBs + 66560;

    hipMemsetAsync(sum, 0, 896*sizeof(float), stream);   // zero sum+sumsq+p

    repack_k<<<dim3(360), dim3(256), 0, stream>>>(
        f1_w, f2_w, g1_w, g2_w, g3_w, oa1_w, oa2_w, oa3_w, WBs);
    convert_k<<<dim3(HW_/256, B_), dim3(256), 0, stream>>>(feat, FEAT, p);

    // sigma branch (p complete after convert_k)
    sigma_k<<<dim3(1), dim3(64), 0, stream>>>(p, s1w, s1b, s2w, s2b, s3w, s3b, gk);

    const dim3 cgrid(10, 40, 8), cblk(256);
    #define MCONV(CIN,CIp,COUT,MT,K,IBN,OST,OM,OCP) \
        mconv_k<CIN,CIp,COUT,MT,K,IBN,OST,OM,OCP><<<cgrid,cblk,0,stream>>>

    const short* G1SRC;
    if (merged){
        // r19: one staging pass -> f1(A1)+stats0, g1(G1O)+stats1
        mconv_fg_k<<<cgrid, cblk, 0, stream>>>(FEAT, w_f1, w_g1, A1, G1O,
                                               sum+0*64, sq+0*64, sum+1*64, sq+1*64);
        // f2 (bn in, 3x3 32->1, tanh) reads A1
        MCONV(32,32, 1,1,3,true ,false,2, 0)(A1, sum+0*64, sq+0*64, f1_g, f1_b,
            w_f2, f2_bias, FUS, nullptr, nullptr, nullptr, nullptr, nullptr);
        G1SRC = G1O;
    } else {
        // fallback = r18 sequence: f1 -> f2 -> g1 (A1 reused)
        MCONV(32,32,32,2,3,false,true ,0,32)(FEAT, nullptr, nullptr, nullptr, nullptr,
            w_f1, nullptr, A1, sum+0*64, sq+0*64, nullptr, nullptr, nullptr);
        MCONV(32,32, 1,1,3,true ,false,2, 0)(A1, sum+0*64, sq+0*64, f1_g, f1_b,
            w_f2, f2_bias, FUS, nullptr, nullptr, nullptr, nullptr, nullptr);
        MCONV(32,32,32,2,5,false,true ,0,32)(FEAT, nullptr, nullptr, nullptr, nullptr,
            w_g1, nullptr, A1, sum+1*64, sq+1*64, nullptr, nullptr, nullptr);
        G1SRC = A1;
    }

    // guid branch: g2 (5x5 32->8, stats) -> g3 (5x5 8->8 +bias)
    MCONV(32,32, 8,1,5,true ,true ,0, 8)(G1SRC, sum+1*64, sq+1*64, g1_g, g1_b,
        w_g2, nullptr, A2, sum+2*64, sq+2*64, nullptr, nullptr, nullptr);
    MCONV( 8, 8, 8,1,5,true ,false,1, 8)(A2, sum+2*64, sq+2*64, g2_g, g2_b,
        w_g3, g3_bias, GUID, nullptr, nullptr, nullptr, nullptr, nullptr);

    // off_aff branch: oa1 (5x5 8->8, stats) -> oa2 (5x5 8->24, stats)
    //                 -> oa3 (5x5 24->24 +bias) fused with deform -> out
    MCONV( 8, 8, 8,1,5,false,true ,0, 8)(GUID, nullptr, nullptr, nullptr, nullptr,
        w_o1, nullptr, A2, sum+3*64, sq+3*64, nullptr, nullptr, nullptr);
    MCONV( 8, 8,24,2,5,true ,true ,0,32)(A2, sum+3*64, sq+3*64, oa1_g, oa1_b,
        w_o2, nullptr, OA2, sum+4*64, sq+4*64, nullptr, nullptr, nullptr);
    MCONV(24,32,24,2,5,true ,false,3, 0)(OA2, sum+4*64, sq+4*64, oa2_g, oa2_b,
        w_o3, oa3_bias, out, nullptr, nullptr, FUS, gk, aff_scale);
    #undef MCONV
}